// Round 1
// baseline (514.528 us; speedup 1.0000x reference)
//
#include <hip/hip_runtime.h>

// Chamfer distance, B=8, N=M=8192, D=3, fp32.
// dist[b,i,j] = |x_i|^2 + |y_j|^2 - 2<x_i,y_j>
// out = mean_j min_i dist + mean_i min_j dist   (scalar)
//
// Strategy: compute-bound fp32 VALU kernel. Each thread owns one point,
// scans all 8192 candidates of its batch with a wave-uniform index
// (broadcast/scalar loads), keeping q = -2*p in registers so the inner
// body is mul+fma+fma(+add folded)+min per pair. Both directions in one
// launch (symmetric roles).

#define B_ 8
#define N_ 8192
#define PTS (B_ * N_)   // 65536 points per set

__global__ __launch_bounds__(256) void chamfer_pre_k(
    const float* __restrict__ x, const float* __restrict__ y,
    float4* __restrict__ px, float4* __restrict__ py) {
  int i = blockIdx.x * 256 + threadIdx.x;   // 0..PTS-1, exact
  float a = x[3 * i], b = x[3 * i + 1], c = x[3 * i + 2];
  px[i] = make_float4(a, b, c, fmaf(a, a, fmaf(b, b, c * c)));
  float d = y[3 * i], e = y[3 * i + 1], f = y[3 * i + 2];
  py[i] = make_float4(d, e, f, fmaf(d, d, fmaf(e, e, f * f)));
}

__global__ __launch_bounds__(256) void chamfer_main_k(
    const float4* __restrict__ px, const float4* __restrict__ py,
    float* __restrict__ out) {
  int gid = blockIdx.x * 256 + threadIdx.x;   // 0 .. 2*PTS-1
  int dir = gid >> 16;                        // 0: own x scan y; 1: own y scan x
  int pid = gid & (PTS - 1);
  const float4* __restrict__ own  = dir ? py : px;
  const float4* __restrict__ cand = dir ? px : py;

  float4 p = own[pid];
  float q0 = -2.0f * p.x, q1 = -2.0f * p.y, q2 = -2.0f * p.z;
  const float4* __restrict__ cb = cand + (pid & ~(N_ - 1));  // batch base

  float m0 = 1e30f, m1 = 1e30f, m2 = 1e30f, m3 = 1e30f;
#pragma unroll 8
  for (int j = 0; j < N_; j += 4) {
    float4 c0 = cb[j + 0];
    float4 c1 = cb[j + 1];
    float4 c2 = cb[j + 2];
    float4 c3 = cb[j + 3];
    m0 = fminf(m0, fmaf(q2, c0.z, fmaf(q1, c0.y, fmaf(q0, c0.x, c0.w))));
    m1 = fminf(m1, fmaf(q2, c1.z, fmaf(q1, c1.y, fmaf(q0, c1.x, c1.w))));
    m2 = fminf(m2, fmaf(q2, c2.z, fmaf(q1, c2.y, fmaf(q0, c2.x, c2.w))));
    m3 = fminf(m3, fmaf(q2, c3.z, fmaf(q1, c3.y, fmaf(q0, c3.x, c3.w))));
  }
  float s = p.w + fminf(fminf(m0, m1), fminf(m2, m3));

  // wave(64) shuffle reduction
  for (int off = 32; off > 0; off >>= 1)
    s += __shfl_down(s, off, 64);

  __shared__ float red[4];
  int lane = threadIdx.x & 63;
  int wv = threadIdx.x >> 6;
  if (lane == 0) red[wv] = s;
  __syncthreads();
  if (threadIdx.x == 0) {
    float t = (red[0] + red[1]) + (red[2] + red[3]);
    atomicAdd(out, t * (1.0f / (float)PTS));
  }
}

extern "C" void kernel_launch(void* const* d_in, const int* in_sizes, int n_in,
                              void* d_out, int out_size, void* d_ws, size_t ws_size,
                              hipStream_t stream) {
  const float* x = (const float*)d_in[0];
  const float* y = (const float*)d_in[1];
  float* out = (float*)d_out;
  float4* px = (float4*)d_ws;          // PTS float4 = 1 MB
  float4* py = px + PTS;               // +1 MB  (ws usage: 2 MB)

  hipMemsetAsync(d_out, 0, sizeof(float), stream);
  chamfer_pre_k<<<PTS / 256, 256, 0, stream>>>(x, y, px, py);
  chamfer_main_k<<<2 * PTS / 256, 256, 0, stream>>>(px, py, out);
}

// Round 2
// 180.189 us; speedup vs baseline: 2.8555x; 2.8555x over previous
//
#include <hip/hip_runtime.h>

// Chamfer distance, B=8, N=M=8192, D=3, fp32.
// out = mean_j min_i dist + mean_i min_j dist, dist = |x|^2+|y|^2-2<x,y>
//
// R2: VALU-bound design. Each thread holds P=8 own-points in registers
// (q=-2p, |p|^2) and scans a CHUNK of candidates; per candidate per wave:
// 1 broadcast float4 load + 32 VALU instrs (vs 1:4 in R1, which was
// VMEM-issue-bound at VALUBusy=20%). Candidate chunk id = wave id, so the
// candidate address is wave-uniform (scalar addressing, broadcast load).
// S=8 chunk-partial mins (with |p|^2 folded in) combine through LDS.

#define B_ 8
#define N_ 8192
#define PTS (B_ * N_)   // 65536 points per set
#define TPB 512
#define P 8             // own points per thread
#define S 8             // candidate chunks == waves per block
#define CHUNK (N_ / S)  // 1024

__global__ __launch_bounds__(256) void chamfer_pre_k(
    const float* __restrict__ x, const float* __restrict__ y,
    float4* __restrict__ px, float4* __restrict__ py) {
  int i = blockIdx.x * 256 + threadIdx.x;   // 0..PTS-1, exact
  float a = x[3 * i], b = x[3 * i + 1], c = x[3 * i + 2];
  px[i] = make_float4(a, b, c, fmaf(a, a, fmaf(b, b, c * c)));
  float d = y[3 * i], e = y[3 * i + 1], f = y[3 * i + 2];
  py[i] = make_float4(d, e, f, fmaf(d, d, fmaf(e, e, f * f)));
}

__global__ __launch_bounds__(TPB) void chamfer_main_k(
    const float4* __restrict__ px, const float4* __restrict__ py,
    float* __restrict__ out) {
  int t = threadIdx.x;
  int lane = t & 63;
  int wv = t >> 6;                      // candidate chunk 0..7 (wave-uniform)
  int slotBase = blockIdx.x * TPB;      // uniform; block owns 512 own-points
  int dir = slotBase >> 16;             // 0: own x scan y; 1: own y scan x
  int ownBase = slotBase & (PTS - 1);   // uniform, multiple of 512
  const float4* __restrict__ own  = dir ? py : px;
  const float4* __restrict__ cand = dir ? px : py;
  // batch base computed from uniform ownBase -> provably wave-uniform address
  const float4* __restrict__ cb = cand + (ownBase & ~(N_ - 1)) + wv * CHUNK;

  float q0[P], q1[P], q2[P], pw[P], mA[P], mB[P];
#pragma unroll
  for (int p = 0; p < P; ++p) {
    float4 o = own[ownBase + lane * P + p];
    q0[p] = -2.0f * o.x; q1[p] = -2.0f * o.y; q2[p] = -2.0f * o.z;
    pw[p] = o.w;
    mA[p] = 1e30f; mB[p] = 1e30f;
  }

#pragma unroll 2
  for (int j = 0; j < CHUNK; j += 2) {
    float4 c0 = cb[j];
    float4 c1 = cb[j + 1];
#pragma unroll
    for (int p = 0; p < P; ++p) {
      mA[p] = fminf(mA[p], fmaf(q2[p], c0.z, fmaf(q1[p], c0.y, fmaf(q0[p], c0.x, c0.w))));
      mB[p] = fminf(mB[p], fmaf(q2[p], c1.z, fmaf(q1[p], c1.y, fmaf(q0[p], c1.x, c1.w))));
    }
  }

  // chunk-partial results (|p|^2 folded: min_c(pw+m_c) == pw+min_c m_c)
  __shared__ float part[TPB][S + 1];    // +1 pad; 18 KB, 1 block/CU
#pragma unroll
  for (int p = 0; p < P; ++p)
    part[lane * P + p][wv] = pw[p] + fminf(mA[p], mB[p]);
  __syncthreads();

  // finalize: thread t combines the S chunk-partials of local point t
  float v = part[t][0];
#pragma unroll
  for (int c = 1; c < S; ++c) v = fminf(v, part[t][c]);

  // block sum -> one atomic
  for (int off = 32; off > 0; off >>= 1) v += __shfl_down(v, off, 64);
  __shared__ float red[S];
  if (lane == 0) red[wv] = v;
  __syncthreads();
  if (t == 0) {
    float s = 0.0f;
#pragma unroll
    for (int c = 0; c < S; ++c) s += red[c];
    atomicAdd(out, s * (1.0f / (float)PTS));
  }
}

extern "C" void kernel_launch(void* const* d_in, const int* in_sizes, int n_in,
                              void* d_out, int out_size, void* d_ws, size_t ws_size,
                              hipStream_t stream) {
  const float* x = (const float*)d_in[0];
  const float* y = (const float*)d_in[1];
  float* out = (float*)d_out;
  float4* px = (float4*)d_ws;          // 1 MB
  float4* py = px + PTS;               // 1 MB

  hipMemsetAsync(d_out, 0, sizeof(float), stream);
  chamfer_pre_k<<<PTS / 256, 256, 0, stream>>>(x, y, px, py);
  chamfer_main_k<<<(2 * PTS) / TPB, TPB, 0, stream>>>(px, py, out);
}

// Round 3
// 150.257 us; speedup vs baseline: 3.4243x; 1.1992x over previous
//
#include <hip/hip_runtime.h>

// Chamfer distance, B=8, N=M=8192, D=3, fp32.
// out = mean_j min_i dist + mean_i min_j dist, dist = |x|^2+|y|^2-2<x,y>
//
// R3: R2 was VALU-latency-stalled at 2 waves/SIMD (VALUBusy 74%, occ 22%).
// - TPB=1024, S=16 candidate chunks -> 4 waves/SIMD (occ ~50%).
// - 4-candidate unroll, min3 accumulation (3.5 VALU/pair vs 4).
// - coalesced float4 pre-pack kernel, memset folded in (2 dispatches).
// Candidate address stays provably wave-uniform -> broadcast/scalar loads.

#define B_ 8
#define N_ 8192
#define PTS (B_ * N_)   // 65536 points per set
#define TPB 1024
#define P 8             // own points per thread (per lane)
#define S 16            // candidate chunks == waves per block
#define CHUNK (N_ / S)  // 512
#define OWN_PER_BLOCK 512

__global__ __launch_bounds__(256) void chamfer_pre_k(
    const float* __restrict__ x, const float* __restrict__ y,
    float4* __restrict__ px, float4* __restrict__ py, float* __restrict__ out) {
  int i = blockIdx.x * 256 + threadIdx.x;   // 0..PTS/4-1; 4 points per thread
  if (i == 0) out[0] = 0.0f;                // fold the memset dispatch
  const float4* xv = (const float4*)x;
  const float4* yv = (const float4*)y;
  float4 a0 = xv[3 * i], a1 = xv[3 * i + 1], a2 = xv[3 * i + 2];
  px[4 * i + 0] = make_float4(a0.x, a0.y, a0.z, fmaf(a0.x, a0.x, fmaf(a0.y, a0.y, a0.z * a0.z)));
  px[4 * i + 1] = make_float4(a0.w, a1.x, a1.y, fmaf(a0.w, a0.w, fmaf(a1.x, a1.x, a1.y * a1.y)));
  px[4 * i + 2] = make_float4(a1.z, a1.w, a2.x, fmaf(a1.z, a1.z, fmaf(a1.w, a1.w, a2.x * a2.x)));
  px[4 * i + 3] = make_float4(a2.y, a2.z, a2.w, fmaf(a2.y, a2.y, fmaf(a2.z, a2.z, a2.w * a2.w)));
  float4 b0 = yv[3 * i], b1 = yv[3 * i + 1], b2 = yv[3 * i + 2];
  py[4 * i + 0] = make_float4(b0.x, b0.y, b0.z, fmaf(b0.x, b0.x, fmaf(b0.y, b0.y, b0.z * b0.z)));
  py[4 * i + 1] = make_float4(b0.w, b1.x, b1.y, fmaf(b0.w, b0.w, fmaf(b1.x, b1.x, b1.y * b1.y)));
  py[4 * i + 2] = make_float4(b1.z, b1.w, b2.x, fmaf(b1.z, b1.z, fmaf(b1.w, b1.w, b2.x * b2.x)));
  py[4 * i + 3] = make_float4(b2.y, b2.z, b2.w, fmaf(b2.y, b2.y, fmaf(b2.z, b2.z, b2.w * b2.w)));
}

__global__ __launch_bounds__(TPB) void chamfer_main_k(
    const float4* __restrict__ px, const float4* __restrict__ py,
    float* __restrict__ out) {
  int t = threadIdx.x;
  int lane = t & 63;
  int wv = t >> 6;                           // candidate chunk 0..15 (uniform per wave)
  int slotBase = blockIdx.x * OWN_PER_BLOCK; // uniform
  int dir = slotBase >> 16;                  // 0: own x scan y; 1: own y scan x
  int ownBase = slotBase & (PTS - 1);        // uniform, multiple of 512
  const float4* __restrict__ own  = dir ? py : px;
  const float4* __restrict__ cand = dir ? px : py;
  const float4* __restrict__ cb = cand + (ownBase & ~(N_ - 1)) + wv * CHUNK;

  float q0[P], q1[P], q2[P], pw[P], mA[P], mB[P];
#pragma unroll
  for (int p = 0; p < P; ++p) {
    float4 o = own[ownBase + lane * P + p];
    q0[p] = -2.0f * o.x; q1[p] = -2.0f * o.y; q2[p] = -2.0f * o.z;
    pw[p] = o.w;
    mA[p] = 1e30f; mB[p] = 1e30f;
  }

#pragma unroll 2
  for (int j = 0; j < CHUNK; j += 4) {
    float4 c0 = cb[j + 0];
    float4 c1 = cb[j + 1];
    float4 c2 = cb[j + 2];
    float4 c3 = cb[j + 3];
#pragma unroll
    for (int p = 0; p < P; ++p) {
      float v0 = fmaf(q2[p], c0.z, fmaf(q1[p], c0.y, fmaf(q0[p], c0.x, c0.w)));
      float v1 = fmaf(q2[p], c1.z, fmaf(q1[p], c1.y, fmaf(q0[p], c1.x, c1.w)));
      mA[p] = fminf(fminf(mA[p], v0), v1);   // -> v_min3_f32
      float v2 = fmaf(q2[p], c2.z, fmaf(q1[p], c2.y, fmaf(q0[p], c2.x, c2.w)));
      float v3 = fmaf(q2[p], c3.z, fmaf(q1[p], c3.y, fmaf(q0[p], c3.x, c3.w)));
      mB[p] = fminf(fminf(mB[p], v2), v3);   // -> v_min3_f32
    }
  }

  // chunk-partial results (|p|^2 folded: min_c(pw+m_c) == pw+min_c m_c)
  __shared__ float part[OWN_PER_BLOCK][S + 1];  // ~34.8 KB
  __shared__ float red[8];
#pragma unroll
  for (int p = 0; p < P; ++p)
    part[lane * P + p][wv] = pw[p] + fminf(mA[p], mB[p]);
  __syncthreads();

  if (t < OWN_PER_BLOCK) {
    float v = part[t][0];
#pragma unroll
    for (int c = 1; c < S; ++c) v = fminf(v, part[t][c]);
    // block sum over 512 values -> 8 wave sums -> one atomic
    for (int off = 32; off > 0; off >>= 1) v += __shfl_down(v, off, 64);
    if (lane == 0) red[wv] = v;
  }
  __syncthreads();
  if (t == 0) {
    float s = 0.0f;
#pragma unroll
    for (int c = 0; c < 8; ++c) s += red[c];
    atomicAdd(out, s * (1.0f / (float)PTS));
  }
}

extern "C" void kernel_launch(void* const* d_in, const int* in_sizes, int n_in,
                              void* d_out, int out_size, void* d_ws, size_t ws_size,
                              hipStream_t stream) {
  const float* x = (const float*)d_in[0];
  const float* y = (const float*)d_in[1];
  float* out = (float*)d_out;
  float4* px = (float4*)d_ws;          // 1 MB
  float4* py = px + PTS;               // 1 MB

  chamfer_pre_k<<<PTS / 4 / 256, 256, 0, stream>>>(x, y, px, py, out);
  chamfer_main_k<<<(2 * PTS) / OWN_PER_BLOCK, TPB, 0, stream>>>(px, py, out);
}

// Round 5
// 141.806 us; speedup vs baseline: 3.6284x; 1.0596x over previous
//
#include <hip/hip_runtime.h>

// Chamfer distance, B=8, N=M=8192, D=3, fp32.
// out = mean_j min_i dist + mean_i min_j dist, dist = |x|^2+|y|^2-2<x,y>
//
// R5: R3 was TA-bound (64 addresses/instr through the texture-address unit
// even for wave-uniform global loads; 2.1M loads * ~32cyc / 256CU == 105us).
// R4's scalar-pipe (s_load) asm crashed; abandoned as too fragile.
// This round: LDS-broadcast candidate delivery + packed-fp32 compute.
//  - candidates staged to LDS in 2048-point tiles (coalesced copy, ~zero TA)
//  - each wave scans its chunk with wave-uniform ds_read_b128 = LDS
//    broadcast; each candidate read ONCE per block (8192 ds_read/CU)
//  - own points packed in float2 pairs -> v_pk_fma_f32 (2 FMAs/instr),
//    candidate components splatted, v_min3_f32 accumulate:
//    ~2-2.5 lane-instr/pair (vs 3.5 scalar)
//  - part[] aliases the tile buffer (LDS 34.8 KB total)

#define B_ 8
#define N_ 8192
#define PTS (B_ * N_)   // 65536 points per set
#define TPB 1024
#define P 8             // own points per thread (per lane)
#define S 16            // waves per block
#define TILE 2048       // candidates per LDS tile (32 KB)
#define NT (N_ / TILE)  // 4 tiles
#define TCHUNK (TILE / S)  // 128 candidates per wave per tile
#define OWN_PER_BLOCK 512

typedef float __attribute__((ext_vector_type(2))) f2;

__global__ __launch_bounds__(256) void chamfer_pre_k(
    const float* __restrict__ x, const float* __restrict__ y,
    float4* __restrict__ px, float4* __restrict__ py, float* __restrict__ out) {
  int i = blockIdx.x * 256 + threadIdx.x;   // 0..PTS/4-1; 4 points per thread
  if (i == 0) out[0] = 0.0f;                // fold the memset dispatch
  const float4* xv = (const float4*)x;
  const float4* yv = (const float4*)y;
  float4 a0 = xv[3 * i], a1 = xv[3 * i + 1], a2 = xv[3 * i + 2];
  px[4 * i + 0] = make_float4(a0.x, a0.y, a0.z, fmaf(a0.x, a0.x, fmaf(a0.y, a0.y, a0.z * a0.z)));
  px[4 * i + 1] = make_float4(a0.w, a1.x, a1.y, fmaf(a0.w, a0.w, fmaf(a1.x, a1.x, a1.y * a1.y)));
  px[4 * i + 2] = make_float4(a1.z, a1.w, a2.x, fmaf(a1.z, a1.z, fmaf(a1.w, a1.w, a2.x * a2.x)));
  px[4 * i + 3] = make_float4(a2.y, a2.z, a2.w, fmaf(a2.y, a2.y, fmaf(a2.z, a2.z, a2.w * a2.w)));
  float4 b0 = yv[3 * i], b1 = yv[3 * i + 1], b2 = yv[3 * i + 2];
  py[4 * i + 0] = make_float4(b0.x, b0.y, b0.z, fmaf(b0.x, b0.x, fmaf(b0.y, b0.y, b0.z * b0.z)));
  py[4 * i + 1] = make_float4(b0.w, b1.x, b1.y, fmaf(b0.w, b0.w, fmaf(b1.x, b1.x, b1.y * b1.y)));
  py[4 * i + 2] = make_float4(b1.z, b1.w, b2.x, fmaf(b1.z, b1.z, fmaf(b1.w, b1.w, b2.x * b2.x)));
  py[4 * i + 3] = make_float4(b2.y, b2.z, b2.w, fmaf(b2.y, b2.y, fmaf(b2.z, b2.z, b2.w * b2.w)));
}

__global__ __launch_bounds__(TPB) void chamfer_main_k(
    const float4* __restrict__ px, const float4* __restrict__ py,
    float* __restrict__ out) {
  // LDS: tile buffer reused (after a barrier) as the partial-min array.
  // sizes: tile = TILE*16 = 32768 B; part+red = 512*17*4 + 32 = 34848 B.
  __shared__ __align__(16) char smraw[OWN_PER_BLOCK * (S + 1) * 4 + 32];
  float4* tile = (float4*)smraw;
  float (*part)[S + 1] = (float (*)[S + 1])smraw;
  float* red = (float*)(smraw + OWN_PER_BLOCK * (S + 1) * 4);

  int t = threadIdx.x;
  int lane = t & 63;
  int wv = t >> 6;                           // 0..15
  int slotBase = blockIdx.x * OWN_PER_BLOCK; // uniform
  int dir = slotBase >> 16;                  // 0: own x scan y; 1: own y scan x
  int ownBase = slotBase & (PTS - 1);        // uniform, multiple of 512
  const float4* __restrict__ own  = dir ? py : px;
  const float4* __restrict__ cand = dir ? px : py;
  const float4* __restrict__ cbatch = cand + (ownBase & ~(N_ - 1));

  // own points, packed in pairs for v_pk_fma_f32
  f2 Q0[4], Q1[4], Q2[4];
  float pw[P], m[P];
#pragma unroll
  for (int pp = 0; pp < 4; ++pp) {
    float4 a = own[ownBase + lane * P + 2 * pp];
    float4 b = own[ownBase + lane * P + 2 * pp + 1];
    Q0[pp] = f2{-2.0f * a.x, -2.0f * b.x};
    Q1[pp] = f2{-2.0f * a.y, -2.0f * b.y};
    Q2[pp] = f2{-2.0f * a.z, -2.0f * b.z};
    pw[2 * pp] = a.w; pw[2 * pp + 1] = b.w;
    m[2 * pp] = 1e30f; m[2 * pp + 1] = 1e30f;
  }

  for (int tt = 0; tt < NT; ++tt) {
    __syncthreads();                         // tile free (prior readers done)
    const float4* __restrict__ src = cbatch + tt * TILE;
#pragma unroll
    for (int k = 0; k < TILE / TPB; ++k)     // 2 coalesced float4 copies
      tile[t + k * TPB] = src[t + k * TPB];
    __syncthreads();

    int base = wv * TCHUNK;                  // wave-uniform -> ds broadcast
#pragma unroll 4
    for (int j = 0; j < TCHUNK; j += 2) {
      float4 c0 = tile[base + j];
      float4 c1 = tile[base + j + 1];
      f2 c0x = {c0.x, c0.x}, c0y = {c0.y, c0.y}, c0z = {c0.z, c0.z}, c0w = {c0.w, c0.w};
      f2 c1x = {c1.x, c1.x}, c1y = {c1.y, c1.y}, c1z = {c1.z, c1.z}, c1w = {c1.w, c1.w};
#pragma unroll
      for (int pp = 0; pp < 4; ++pp) {
        f2 d0 = __builtin_elementwise_fma(Q2[pp], c0z,
                 __builtin_elementwise_fma(Q1[pp], c0y,
                  __builtin_elementwise_fma(Q0[pp], c0x, c0w)));
        f2 d1 = __builtin_elementwise_fma(Q2[pp], c1z,
                 __builtin_elementwise_fma(Q1[pp], c1y,
                  __builtin_elementwise_fma(Q0[pp], c1x, c1w)));
        m[2 * pp]     = fminf(fminf(m[2 * pp],     d0.x), d1.x);  // v_min3
        m[2 * pp + 1] = fminf(fminf(m[2 * pp + 1], d0.y), d1.y);  // v_min3
      }
    }
  }

  __syncthreads();          // done reading tile; alias as part[]
#pragma unroll
  for (int p = 0; p < P; ++p)
    part[lane * P + p][wv] = pw[p] + m[p];   // |p|^2 folded in
  __syncthreads();

  if (t < OWN_PER_BLOCK) {
    float v = part[t][0];
#pragma unroll
    for (int c = 1; c < S; ++c) v = fminf(v, part[t][c]);
    for (int off = 32; off > 0; off >>= 1) v += __shfl_down(v, off, 64);
    if (lane == 0) red[t >> 6] = v;
  }
  __syncthreads();
  if (t == 0) {
    float s = 0.0f;
#pragma unroll
    for (int c = 0; c < 8; ++c) s += red[c];
    atomicAdd(out, s * (1.0f / (float)PTS));
  }
}

extern "C" void kernel_launch(void* const* d_in, const int* in_sizes, int n_in,
                              void* d_out, int out_size, void* d_ws, size_t ws_size,
                              hipStream_t stream) {
  const float* x = (const float*)d_in[0];
  const float* y = (const float*)d_in[1];
  float* out = (float*)d_out;
  float4* px = (float4*)d_ws;          // 1 MB
  float4* py = px + PTS;               // 1 MB

  chamfer_pre_k<<<PTS / 4 / 256, 256, 0, stream>>>(x, y, px, py, out);
  chamfer_main_k<<<(2 * PTS) / OWN_PER_BLOCK, TPB, 0, stream>>>(px, py, out);
}

// Round 6
// 138.145 us; speedup vs baseline: 3.7245x; 1.0265x over previous
//
#include <hip/hip_runtime.h>

// Chamfer distance, B=8, N=M=8192, D=3, fp32.
// out = mean_j min_i dist + mean_i min_j dist, dist = |x|^2+|y|^2-2<x,y>
//
// R6: R5 showed joint VALU+DS-pipe bound (~63us VALU at m07's sustained
// rate + ~41us DS, imperfect overlap). Both scale with per-candidate
// amortization. This round: P=16 own points/lane (1024/block); each block
// scans HALF the candidates (4096) so grid stays 256 = 1 block/CU.
// Halves ds_read/pair and drops VALU to ~1-1.75 instr/pair (pk_fma +
// min3). Cross-block combine of the two candidate halves via exact
// ordered-uint atomicMin (LDS per block, then global). |own|^2 deferred
// to a small final reduction kernel.

#define B_ 8
#define N_ 8192
#define PTS (B_ * N_)    // 65536 points per set
#define TPB 1024
#define P 16             // own points per lane
#define S 16             // waves per block
#define TILE 2048        // candidates staged per LDS tile (32 KB)
#define CANDS 4096       // candidates per block (half a batch)
#define NT (CANDS / TILE)   // 2
#define TCHUNK (TILE / S)   // 128 candidates per wave per tile

typedef float __attribute__((ext_vector_type(2))) f2;

// Exact monotone float -> uint map (for atomicMin) and inverse.
__device__ __forceinline__ unsigned enc(float f) {
  unsigned u = __float_as_uint(f);
  return ((int)u < 0) ? ~u : (u | 0x80000000u);
}
__device__ __forceinline__ float dec(unsigned k) {
  unsigned u = ((int)k < 0) ? (k & 0x7fffffffu) : ~k;
  return __uint_as_float(u);
}

__global__ __launch_bounds__(256) void chamfer_pre_k(
    const float* __restrict__ x, const float* __restrict__ y,
    float4* __restrict__ px, float4* __restrict__ py,
    unsigned* __restrict__ gmin, float* __restrict__ out) {
  int i = blockIdx.x * 256 + threadIdx.x;   // 0..PTS/4-1; 4 points per thread
  if (i == 0) out[0] = 0.0f;
#pragma unroll
  for (int k = 0; k < 8; ++k) gmin[8 * i + k] = 0xFFFFFFFFu;  // +inf encoded
  const float4* xv = (const float4*)x;
  const float4* yv = (const float4*)y;
  float4 a0 = xv[3 * i], a1 = xv[3 * i + 1], a2 = xv[3 * i + 2];
  px[4 * i + 0] = make_float4(a0.x, a0.y, a0.z, fmaf(a0.x, a0.x, fmaf(a0.y, a0.y, a0.z * a0.z)));
  px[4 * i + 1] = make_float4(a0.w, a1.x, a1.y, fmaf(a0.w, a0.w, fmaf(a1.x, a1.x, a1.y * a1.y)));
  px[4 * i + 2] = make_float4(a1.z, a1.w, a2.x, fmaf(a1.z, a1.z, fmaf(a1.w, a1.w, a2.x * a2.x)));
  px[4 * i + 3] = make_float4(a2.y, a2.z, a2.w, fmaf(a2.y, a2.y, fmaf(a2.z, a2.z, a2.w * a2.w)));
  float4 b0 = yv[3 * i], b1 = yv[3 * i + 1], b2 = yv[3 * i + 2];
  py[4 * i + 0] = make_float4(b0.x, b0.y, b0.z, fmaf(b0.x, b0.x, fmaf(b0.y, b0.y, b0.z * b0.z)));
  py[4 * i + 1] = make_float4(b0.w, b1.x, b1.y, fmaf(b0.w, b0.w, fmaf(b1.x, b1.x, b1.y * b1.y)));
  py[4 * i + 2] = make_float4(b1.z, b1.w, b2.x, fmaf(b1.z, b1.z, fmaf(b1.w, b1.w, b2.x * b2.x)));
  py[4 * i + 3] = make_float4(b2.y, b2.z, b2.w, fmaf(b2.y, b2.y, fmaf(b2.z, b2.z, b2.w * b2.w)));
}

__global__ __launch_bounds__(TPB, 1) void chamfer_main_k(
    const float4* __restrict__ px, const float4* __restrict__ py,
    unsigned* __restrict__ gmin) {
  __shared__ float4 tile[TILE];         // 32 KB
  __shared__ unsigned minarr[1024];     // 4 KB, encoded partial mins

  int t = threadIdx.x;
  int lane = t & 63;
  int wv = t >> 6;                      // 0..15
  int bid = blockIdx.x;                 // 256 blocks
  int dir = bid >> 7;                   // 0: own x scan y; 1: own y scan x
  int bb = bid & 127;
  int batch = bb >> 4;
  int sub = bb & 15;
  int ownSeg = sub & 7;                 // which 1024-pt own segment
  int candHalf = sub >> 3;              // which 4096-cand half
  const float4* __restrict__ own  = dir ? py : px;
  const float4* __restrict__ cand = dir ? px : py;
  int ownBase = batch * N_ + ownSeg * 1024;
  const float4* __restrict__ cb = cand + batch * N_ + candHalf * CANDS;
  unsigned* __restrict__ gm = gmin + dir * PTS + ownBase;

  minarr[t] = 0xFFFFFFFFu;              // t < 1024 always

  // own points, packed in pairs for v_pk_fma_f32. point id = p*64 + lane.
  f2 Q0[8], Q1[8], Q2[8];
  float m[P];
#pragma unroll
  for (int pp = 0; pp < 8; ++pp) {
    float4 a = own[ownBase + (2 * pp) * 64 + lane];
    float4 b = own[ownBase + (2 * pp + 1) * 64 + lane];
    Q0[pp] = f2{-2.0f * a.x, -2.0f * b.x};
    Q1[pp] = f2{-2.0f * a.y, -2.0f * b.y};
    Q2[pp] = f2{-2.0f * a.z, -2.0f * b.z};
    m[2 * pp] = 1e30f; m[2 * pp + 1] = 1e30f;
  }

  for (int tt = 0; tt < NT; ++tt) {
    if (tt) __syncthreads();            // prior tile's readers done
    const float4* __restrict__ src = cb + tt * TILE;
#pragma unroll
    for (int k = 0; k < TILE / TPB; ++k)   // coalesced staging
      tile[t + k * TPB] = src[t + k * TPB];
    __syncthreads();

    int base = wv * TCHUNK;             // wave-uniform -> LDS broadcast
#pragma unroll 4
    for (int j = 0; j < TCHUNK; j += 2) {
      float4 c0 = tile[base + j];
      float4 c1 = tile[base + j + 1];
      f2 c0x = {c0.x, c0.x}, c0y = {c0.y, c0.y}, c0z = {c0.z, c0.z}, c0w = {c0.w, c0.w};
      f2 c1x = {c1.x, c1.x}, c1y = {c1.y, c1.y}, c1z = {c1.z, c1.z}, c1w = {c1.w, c1.w};
#pragma unroll
      for (int pp = 0; pp < 8; ++pp) {
        f2 dA = __builtin_elementwise_fma(Q2[pp], c0z,
                 __builtin_elementwise_fma(Q1[pp], c0y,
                  __builtin_elementwise_fma(Q0[pp], c0x, c0w)));
        f2 dB = __builtin_elementwise_fma(Q2[pp], c1z,
                 __builtin_elementwise_fma(Q1[pp], c1y,
                  __builtin_elementwise_fma(Q0[pp], c1x, c1w)));
        m[2 * pp]     = fminf(fminf(m[2 * pp],     dA.x), dB.x);  // v_min3
        m[2 * pp + 1] = fminf(fminf(m[2 * pp + 1], dA.y), dB.y);  // v_min3
      }
    }
  }

  // combine 16 waves' partials in LDS (encoded uint atomicMin = ds_min_u32)
#pragma unroll
  for (int p = 0; p < P; ++p)
    atomicMin(&minarr[p * 64 + lane], enc(m[p]));
  __syncthreads();

  // push block partial to global (other candidate-half block combines here)
  atomicMin(&gm[t], minarr[t]);         // t < 1024 always
}

__global__ __launch_bounds__(256) void chamfer_final_k(
    const float4* __restrict__ px, const float4* __restrict__ py,
    const unsigned* __restrict__ gmin, float* __restrict__ out) {
  int i = blockIdx.x * 256 + threadIdx.x;   // 0..16383, 8 entries each
  float s = 0.0f;
#pragma unroll
  for (int e = 0; e < 8; ++e) {
    int g = 8 * i + e;                  // 0 .. 2*PTS-1
    int id = g & (PTS - 1);
    float pw = (g >= PTS) ? py[id].w : px[id].w;
    s += dec(gmin[g]) + pw;
  }
  for (int off = 32; off > 0; off >>= 1) s += __shfl_down(s, off, 64);
  __shared__ float red[4];
  int lane = threadIdx.x & 63, wv = threadIdx.x >> 6;
  if (lane == 0) red[wv] = s;
  __syncthreads();
  if (threadIdx.x == 0) {
    float tt = (red[0] + red[1]) + (red[2] + red[3]);
    atomicAdd(out, tt * (1.0f / (float)PTS));
  }
}

extern "C" void kernel_launch(void* const* d_in, const int* in_sizes, int n_in,
                              void* d_out, int out_size, void* d_ws, size_t ws_size,
                              hipStream_t stream) {
  const float* x = (const float*)d_in[0];
  const float* y = (const float*)d_in[1];
  float* out = (float*)d_out;
  float4* px = (float4*)d_ws;                     // 1 MB
  float4* py = px + PTS;                          // 1 MB
  unsigned* gmin = (unsigned*)(py + PTS);         // 2*PTS uints = 512 KB

  chamfer_pre_k<<<PTS / 4 / 256, 256, 0, stream>>>(x, y, px, py, gmin, out);
  chamfer_main_k<<<256, TPB, 0, stream>>>(px, py, gmin);
  chamfer_final_k<<<2 * PTS / 8 / 256, 256, 0, stream>>>(px, py, gmin, out);
}

// Round 7
// 131.840 us; speedup vs baseline: 3.9027x; 1.0478x over previous
//
#include <hip/hip_runtime.h>

// Chamfer distance, B=8, N=M=8192, D=3, fp32 — MFMA edition.
// dist[i][j] = nx_i + ny_j - 2 x_i.y_j, out = mean(min_i) + mean(min_j).
//
// R7: scan-style fp32 plateaued ~90us (VALU floor ~2 instr/pair). Move the
// distance computation to the matrix pipe: ONE v_mfma_f32_32x32x16_bf16 per
// 32x32 tile computes FINAL distances via K-packing (K=16 >= 13 terms):
//   A row i (k0..12):  [ah0 ah1 ah2  ah0 ah1 ah2  al0 al1 al2  nxh nxl 1 1]
//   B col j (k0..12):  [yh0 yh1 yh2  yl0 yl1 yl2  yh0 yh1 yh2  1 1 nyh nyl]
// with ah=bf16(-2x), al=bf16(-2x-ah), yh=bf16(y), yl=residual, norms split.
// acc = -2x.y + nx + ny + O(1e-5). Each pair computed ONCE; both direction
// mins extracted from the accumulator (row-min in regs + butterfly,
// col-min via min3 tree + LDS atomicMin), combined across blocks by global
// encoded-uint atomicMin (R6-proven). 
// A/B frag layout: m/n = lane&31, k = 8*(lane>>5)+reg (standard CDNA);
// C/D layout (verified m74/m101): col = lane&31, row=(r&3)+8*(r>>2)+4*(lane>>5).

#define B_ 8
#define N_ 8192
#define PTS (B_ * N_)        // 65536 per set
#define TPB 1024

typedef short bf16x8 __attribute__((ext_vector_type(8)));
typedef float f32x16 __attribute__((ext_vector_type(16)));

__device__ __forceinline__ unsigned enc(float f) {
  unsigned u = __float_as_uint(f);
  return ((int)u < 0) ? ~u : (u | 0x80000000u);
}
__device__ __forceinline__ float dec(unsigned k) {
  unsigned u = ((int)k < 0) ? (k & 0x7fffffffu) : ~k;
  return __uint_as_float(u);
}
__device__ __forceinline__ unsigned b16(float f) {   // fp32 -> bf16 bits (RNE)
  unsigned u = __float_as_uint(f);
  return (u + 0x7FFFu + ((u >> 16) & 1u)) >> 16;
}
__device__ __forceinline__ float bf(unsigned h) { return __uint_as_float(h << 16); }

// ---- pre: build A-frags (from x) and B-frags (from y), init gmin/out ----
__global__ __launch_bounds__(256) void chamfer_pre_k(
    const float* __restrict__ x, const float* __restrict__ y,
    uint4* __restrict__ afrag, uint4* __restrict__ bfrag,
    unsigned* __restrict__ gmin, float* __restrict__ out) {
  int p = blockIdx.x * 256 + threadIdx.x;      // 0..PTS-1
  if (p == 0) out[0] = 0.0f;
  gmin[p] = 0xFFFFFFFFu;
  gmin[p + PTS] = 0xFFFFFFFFu;
  const unsigned one = 0x3F80u;
  int tile = p >> 5, m = p & 31;

  // A side: vector -2x split hi/lo, norm of x split hi/lo
  float x0 = x[3 * p], x1 = x[3 * p + 1], x2 = x[3 * p + 2];
  float nx = fmaf(x0, x0, fmaf(x1, x1, x2 * x2));
  float a0 = -2.0f * x0, a1 = -2.0f * x1, a2 = -2.0f * x2;
  unsigned ah0 = b16(a0), ah1 = b16(a1), ah2 = b16(a2);
  unsigned al0 = b16(a0 - bf(ah0)), al1 = b16(a1 - bf(ah1)), al2 = b16(a2 - bf(ah2));
  unsigned nxh = b16(nx), nxl = b16(nx - bf(nxh));
  // half0: k0-7 = [ah0 ah1 ah2 ah0 ah1 ah2 al0 al1]
  afrag[tile * 64 + m]      = make_uint4(ah0 | (ah1 << 16), ah2 | (ah0 << 16),
                                         ah1 | (ah2 << 16), al0 | (al1 << 16));
  // half1: k8-15 = [al2 nxh nxl 1 1 0 0 0]
  afrag[tile * 64 + 32 + m] = make_uint4(al2 | (nxh << 16), nxl | (one << 16),
                                         one, 0u);

  // B side: y split hi/lo, norm split
  float y0 = y[3 * p], y1 = y[3 * p + 1], y2 = y[3 * p + 2];
  float ny = fmaf(y0, y0, fmaf(y1, y1, y2 * y2));
  unsigned yh0 = b16(y0), yh1 = b16(y1), yh2 = b16(y2);
  unsigned yl0 = b16(y0 - bf(yh0)), yl1 = b16(y1 - bf(yh1)), yl2 = b16(y2 - bf(yh2));
  unsigned nyh = b16(ny), nyl = b16(ny - bf(nyh));
  // half0: k0-7 = [yh0 yh1 yh2 yl0 yl1 yl2 yh0 yh1]
  bfrag[tile * 64 + m]      = make_uint4(yh0 | (yh1 << 16), yh2 | (yl0 << 16),
                                         yl1 | (yl2 << 16), yh0 | (yh1 << 16));
  // half1: k8-15 = [yh2 1 1 nyh nyl 0 0 0]
  bfrag[tile * 64 + 32 + m] = make_uint4(yh2 | (one << 16), one | (nyh << 16),
                                         nyl, 0u);
}

// ---- main: 256 blocks; block = (batch, ownSeg of 1024 x-pts, candSeg of 2048 y-pts)
__global__ __launch_bounds__(TPB, 1) void chamfer_main_k(
    const uint4* __restrict__ afrag, const uint4* __restrict__ bfrag,
    unsigned* __restrict__ gmin) {
  __shared__ uint4 ldsB[64 * 64];        // 64 KB: 64 cand tiles of B-frags
  __shared__ unsigned cminLds[2048];     // 8 KB: per-candidate col-min

  int t = threadIdx.x, lane = t & 63, w = t >> 6;   // 16 waves
  int b = blockIdx.x;
  int batch = b >> 5, sub = b & 31, ownSeg = sub & 7, candSeg = sub >> 3;

  cminLds[t] = 0xFFFFFFFFu;
  cminLds[t + 1024] = 0xFFFFFFFFu;

  const uint4* __restrict__ bsrc = bfrag + (batch * 256 + candSeg * 64) * 64;
#pragma unroll
  for (int k = 0; k < 4; ++k)            // stage 64 KB, coalesced
    ldsB[t + k * 1024] = bsrc[t + k * 1024];

  int atile = batch * 256 + ownSeg * 32 + w * 2;    // wave owns 2 A-tiles
  bf16x8 A0 = __builtin_bit_cast(bf16x8, afrag[atile * 64 + lane]);
  bf16x8 A1 = __builtin_bit_cast(bf16x8, afrag[(atile + 1) * 64 + lane]);
  __syncthreads();

  f32x16 z = {0.f,0.f,0.f,0.f,0.f,0.f,0.f,0.f,0.f,0.f,0.f,0.f,0.f,0.f,0.f,0.f};
  f32x16 rm0, rm1;
#pragma unroll
  for (int r = 0; r < 16; ++r) { rm0[r] = 1e30f; rm1[r] = 1e30f; }

  for (int c = 0; c < 64; ++c) {
    int ct = (c + w * 4) & 63;           // stagger waves across cand tiles
    bf16x8 Bf = __builtin_bit_cast(bf16x8, ldsB[ct * 64 + lane]);
    f32x16 acc0 = __builtin_amdgcn_mfma_f32_32x32x16_bf16(A0, Bf, z, 0, 0, 0);
    f32x16 acc1 = __builtin_amdgcn_mfma_f32_32x32x16_bf16(A1, Bf, z, 0, 0, 0);

    // row-min accumulators (per lane: 16 rows x this lane's col)
#pragma unroll
    for (int r = 0; r < 16; ++r) {
      rm0[r] = fminf(rm0[r], acc0[r]);
      rm1[r] = fminf(rm1[r], acc1[r]);
    }
    // col-min: fold 32 values (64 own rows, this col) -> min3 tree
    float cv = fminf(fminf(acc0[0], acc0[1]), acc0[2]);
#pragma unroll
    for (int r = 3; r < 15; r += 2) cv = fminf(fminf(cv, acc0[r]), acc0[r + 1]);
    cv = fminf(cv, acc0[15]);
#pragma unroll
    for (int r = 0; r < 16; r += 2) cv = fminf(fminf(cv, acc1[r]), acc1[r + 1]);
    cv = fminf(cv, __shfl_xor(cv, 32, 64));          // merge lane-halves
    if (lane < 32) atomicMin(&cminLds[ct * 32 + lane], enc(cv));
  }

  // merge row-mins across the 32 lanes of each half (butterfly)
#pragma unroll
  for (int msk = 1; msk <= 16; msk <<= 1) {
#pragma unroll
    for (int r = 0; r < 16; ++r) {
      rm0[r] = fminf(rm0[r], __shfl_xor(rm0[r], msk, 64));
      rm1[r] = fminf(rm1[r], __shfl_xor(rm1[r], msk, 64));
    }
  }
  // push: lanes (lane&31)<16 each own one reg r=lane&15 of their half
  if ((lane & 31) < 16) {
    int r = lane & 15, h = lane >> 5;
    float s0 = rm0[0], s1 = rm1[0];
#pragma unroll
    for (int q = 1; q < 16; ++q) {
      bool sel = (r == q);
      s0 = sel ? rm0[q] : s0;
      s1 = sel ? rm1[q] : s1;
    }
    int rowl = w * 64 + (r & 3) + 8 * (r >> 2) + 4 * h;
    int gbase = batch * 8192 + ownSeg * 1024;
    atomicMin(&gmin[gbase + rowl], enc(s0));
    atomicMin(&gmin[gbase + rowl + 32], enc(s1));
  }

  __syncthreads();
  int cgb = PTS + batch * 8192 + candSeg * 2048;
  atomicMin(&gmin[cgb + t], cminLds[t]);
  atomicMin(&gmin[cgb + 1024 + t], cminLds[t + 1024]);
}

// ---- final: sum all 2*PTS encoded mins -> scalar ----
__global__ __launch_bounds__(256) void chamfer_final_k(
    const unsigned* __restrict__ gmin, float* __restrict__ out) {
  int i = blockIdx.x * 256 + threadIdx.x;   // 16384 threads, 8 entries each
  const uint4* g = (const uint4*)gmin;
  uint4 u0 = g[2 * i], u1 = g[2 * i + 1];
  float s = dec(u0.x) + dec(u0.y) + dec(u0.z) + dec(u0.w)
          + dec(u1.x) + dec(u1.y) + dec(u1.z) + dec(u1.w);
  for (int off = 32; off > 0; off >>= 1) s += __shfl_down(s, off, 64);
  __shared__ float red[4];
  int lane = threadIdx.x & 63, wv = threadIdx.x >> 6;
  if (lane == 0) red[wv] = s;
  __syncthreads();
  if (threadIdx.x == 0) {
    float tt = (red[0] + red[1]) + (red[2] + red[3]);
    atomicAdd(out, tt * (1.0f / (float)PTS));
  }
}

extern "C" void kernel_launch(void* const* d_in, const int* in_sizes, int n_in,
                              void* d_out, int out_size, void* d_ws, size_t ws_size,
                              hipStream_t stream) {
  const float* x = (const float*)d_in[0];
  const float* y = (const float*)d_in[1];
  float* out = (float*)d_out;
  uint4* afrag = (uint4*)d_ws;                        // 2048 tiles * 1KB = 2 MB
  uint4* bfrag = afrag + 2048 * 64;                   // 2 MB
  unsigned* gmin = (unsigned*)(bfrag + 2048 * 64);    // 512 KB

  chamfer_pre_k<<<PTS / 256, 256, 0, stream>>>(x, y, afrag, bfrag, gmin, out);
  chamfer_main_k<<<256, TPB, 0, stream>>>(afrag, bfrag, gmin);
  chamfer_final_k<<<2 * PTS / 8 / 256, 256, 0, stream>>>(gmin, out);
}

// Round 8
// 97.086 us; speedup vs baseline: 5.2997x; 1.3580x over previous
//
#include <hip/hip_runtime.h>

// Chamfer distance, B=8, N=M=8192, D=3, fp32 — single-kernel MFMA edition.
// dist[i][j] = nx_i + ny_j - 2 x_i.y_j; out = mean(min_j dist) + mean(min_i dist).
//
// R8: R7's fused row+col extraction cost ~54 VALU + shfl + LDS-atomic per
// 1024-pair tile and kept 49us of pre/final dispatch overhead. This round:
//  - row-min ONLY, run both directions (MFMA was 8% util; doubling it is free)
//    -> extraction is 16 v_min3_f32 per 2 tiles, nothing else in the loop
//  - every row's min completes inside one wave -> no gmin, no atomics, no
//    final kernel; block partial-sums -> one atomicAdd
//  - ONE kernel: B-frags built into LDS from raw floats per 1024-cand chunk,
//    A-frags built in registers (K=16 packing validated in R7:
//    A=[ah,ah,al | al2,nxh,nxl,1,1], B=[yh,yl,yh | yh2,1,1,nyh,nyl])
//  - 512 blocks x 512 thr = 2 blocks/CU, 8 waves: wave owns one 32-row tile,
//    scans all 8192 candidates of its batch.

#define B_ 8
#define N_ 8192
#define PTS (B_ * N_)        // 65536 per set
#define TPB 512

typedef short bf16x8 __attribute__((ext_vector_type(8)));
typedef float f32x16 __attribute__((ext_vector_type(16)));

__device__ __forceinline__ unsigned b16(float f) {   // fp32 -> bf16 bits (RNE)
  unsigned u = __float_as_uint(f);
  return (u + 0x7FFFu + ((u >> 16) & 1u)) >> 16;
}
__device__ __forceinline__ float bf(unsigned h) { return __uint_as_float(h << 16); }

__global__ __launch_bounds__(TPB) void chamfer_k(
    const float* __restrict__ x, const float* __restrict__ y,
    float* __restrict__ out) {
  __shared__ uint4 ldsFrag[32 * 64];      // 32 KB: one 1024-candidate chunk
  __shared__ float red[8];

  const unsigned one = 0x3F80u;
  int t = threadIdx.x, lane = t & 63, w = t >> 6;   // 8 waves
  int b = blockIdx.x;                    // 512 blocks
  int dir = b >> 8;                      // 0: rows=x scan y; 1: rows=y scan x
  int bb = b & 255;
  int batch = bb >> 5;
  int rowSeg = bb & 31;                  // 32 segs of 256 rows
  const float* __restrict__ own  = dir ? y : x;
  const float* __restrict__ cand = dir ? x : y;

  // ---- A-frag (one 32-row tile per wave), built in registers ----
  int m = lane & 31;
  int row0 = batch * N_ + rowSeg * 256 + w * 32;    // wave's first row
  const float* po = own + 3 * (row0 + m);
  float v0 = po[0], v1 = po[1], v2 = po[2];
  float nv = fmaf(v0, v0, fmaf(v1, v1, v2 * v2));
  float a0 = -2.0f * v0, a1 = -2.0f * v1, a2 = -2.0f * v2;
  unsigned ah0 = b16(a0), ah1 = b16(a1), ah2 = b16(a2);
  unsigned al0 = b16(a0 - bf(ah0)), al1 = b16(a1 - bf(ah1)), al2 = b16(a2 - bf(ah2));
  unsigned nh = b16(nv), nl = b16(nv - bf(nh));
  uint4 h0 = make_uint4(ah0 | (ah1 << 16), ah2 | (ah0 << 16),
                        ah1 | (ah2 << 16), al0 | (al1 << 16));
  uint4 h1 = make_uint4(al2 | (nh << 16), nl | (one << 16), one, 0u);
  uint4 afr;
  afr.x = (lane < 32) ? h0.x : h1.x;
  afr.y = (lane < 32) ? h0.y : h1.y;
  afr.z = (lane < 32) ? h0.z : h1.z;
  afr.w = (lane < 32) ? h0.w : h1.w;
  bf16x8 A = __builtin_bit_cast(bf16x8, afr);

  f32x16 z = {0.f,0.f,0.f,0.f,0.f,0.f,0.f,0.f,0.f,0.f,0.f,0.f,0.f,0.f,0.f,0.f};
  f32x16 rm;
#pragma unroll
  for (int r = 0; r < 16; ++r) rm[r] = 1e30f;

  const float* cbb = cand + batch * N_ * 3;
  for (int ch = 0; ch < 8; ++ch) {
    __syncthreads();                     // prior chunk's readers done
    const float* cb = cbb + ch * 1024 * 3;
#pragma unroll
    for (int q = 0; q < 2; ++q) {        // thread builds 2 candidates' frags
      int p = 2 * t + q;                 // 0..1023 within chunk
      float c0 = cb[3 * p], c1 = cb[3 * p + 1], c2 = cb[3 * p + 2];
      float nc = fmaf(c0, c0, fmaf(c1, c1, c2 * c2));
      unsigned yh0 = b16(c0), yh1 = b16(c1), yh2 = b16(c2);
      unsigned yl0 = b16(c0 - bf(yh0)), yl1 = b16(c1 - bf(yh1)), yl2 = b16(c2 - bf(yh2));
      unsigned ch_ = b16(nc), cl_ = b16(nc - bf(ch_));
      int tt = p >> 5, mm = p & 31;
      ldsFrag[tt * 64 + mm]      = make_uint4(yh0 | (yh1 << 16), yh2 | (yl0 << 16),
                                              yl1 | (yl2 << 16), yh0 | (yh1 << 16));
      ldsFrag[tt * 64 + 32 + mm] = make_uint4(yh2 | (one << 16), one | (ch_ << 16),
                                              cl_, 0u);
    }
    __syncthreads();

#pragma unroll 4
    for (int i = 0; i < 16; ++i) {       // 32 tiles, 2 per iter
      bf16x8 B0 = __builtin_bit_cast(bf16x8, ldsFrag[(2 * i) * 64 + lane]);
      bf16x8 B1 = __builtin_bit_cast(bf16x8, ldsFrag[(2 * i + 1) * 64 + lane]);
      f32x16 acc0 = __builtin_amdgcn_mfma_f32_32x32x16_bf16(A, B0, z, 0, 0, 0);
      f32x16 acc1 = __builtin_amdgcn_mfma_f32_32x32x16_bf16(A, B1, z, 0, 0, 0);
#pragma unroll
      for (int r = 0; r < 16; ++r)
        rm[r] = fminf(fminf(rm[r], acc0[r]), acc1[r]);   // v_min3_f32
    }
  }

  // ---- epilogue: fold cols (32 lanes/half), sum 32 row-mins, block sum ----
#pragma unroll
  for (int msk = 1; msk <= 16; msk <<= 1) {
#pragma unroll
    for (int r = 0; r < 16; ++r)
      rm[r] = fminf(rm[r], __shfl_xor(rm[r], msk, 64));
  }
  float s = 0.0f;
#pragma unroll
  for (int r = 0; r < 16; ++r) s += rm[r];   // sum of this half's 16 row-mins
  s += __shfl_xor(s, 32, 64);                // + other half -> 32-row tile sum
  if (lane == 0) red[w] = s;
  __syncthreads();
  if (t == 0) {
    float bs = 0.0f;
#pragma unroll
    for (int c = 0; c < 8; ++c) bs += red[c];
    atomicAdd(out, bs * (1.0f / (float)PTS));
  }
}

extern "C" void kernel_launch(void* const* d_in, const int* in_sizes, int n_in,
                              void* d_out, int out_size, void* d_ws, size_t ws_size,
                              hipStream_t stream) {
  const float* x = (const float*)d_in[0];
  const float* y = (const float*)d_in[1];
  float* out = (float*)d_out;
  hipMemsetAsync(out, 0, sizeof(float), stream);
  chamfer_k<<<512, TPB, 0, stream>>>(x, y, out);
}

// Round 9
// 95.562 us; speedup vs baseline: 5.3842x; 1.0159x over previous
//
#include <hip/hip_runtime.h>

// Chamfer distance, B=8, N=M=8192, D=3, fp32 — single-kernel MFMA edition.
// dist[i][j] = nx_i + ny_j - 2 x_i.y_j; out = mean(min_j) + mean(min_i).
//
// R9 (on R8's validated K=16 bf16-split packing):
//   A row = [ah0 ah1 ah2 ah0 ah1 ah2 al0 al1 | al2 nxh nxl 1 1 0 0 0]
//   B col = [yh0 yh1 yh2 yl0 yl1 yl2 yh0 yh1 | yh2 1 1 nyh nyl 0 0 0]
// -> one 32x32x16 MFMA emits 1024 FINAL distances (err ~1e-5).
// R8 was latency/barrier-bound (all pipes <50%) + 3.08M LDS write conflicts.
// Fixes:
//  - staging map p = t, t+512: contiguous lanes -> conflict-free ds_write_b128
//  - double-buffered 32KB chunks: build ch+1 during compute on ch;
//    ONE barrier per chunk, global-load latency hidden under MFMA/min3
//  - 4 B-tiles per iter, 2 independent min-accu sets (rmA/rmB) for ILP
//  - __launch_bounds__(512,4) pins 4 waves/SIMD (2 blocks/CU, 128KB LDS)

#define B_ 8
#define N_ 8192
#define PTS (B_ * N_)        // 65536 per set
#define TPB 512

typedef short bf16x8 __attribute__((ext_vector_type(8)));
typedef float f32x16 __attribute__((ext_vector_type(16)));

__device__ __forceinline__ unsigned b16(float f) {   // fp32 -> bf16 bits (RNE)
  unsigned u = __float_as_uint(f);
  return (u + 0x7FFFu + ((u >> 16) & 1u)) >> 16;
}
__device__ __forceinline__ float bf(unsigned h) { return __uint_as_float(h << 16); }

__device__ __forceinline__ void build_chunk(const float* __restrict__ cb,
                                            uint4* __restrict__ dst, int t) {
  const unsigned one = 0x3F80u;
#pragma unroll
  for (int q = 0; q < 2; ++q) {
    int p = t + q * TPB;                 // contiguous in lane -> no conflicts
    float c0 = cb[3 * p], c1 = cb[3 * p + 1], c2 = cb[3 * p + 2];
    float nc = fmaf(c0, c0, fmaf(c1, c1, c2 * c2));
    unsigned yh0 = b16(c0), yh1 = b16(c1), yh2 = b16(c2);
    unsigned yl0 = b16(c0 - bf(yh0)), yl1 = b16(c1 - bf(yh1)), yl2 = b16(c2 - bf(yh2));
    unsigned nh = b16(nc), nl = b16(nc - bf(nh));
    int tt = p >> 5, mm = p & 31;
    dst[tt * 64 + mm]      = make_uint4(yh0 | (yh1 << 16), yh2 | (yl0 << 16),
                                        yl1 | (yl2 << 16), yh0 | (yh1 << 16));
    dst[tt * 64 + 32 + mm] = make_uint4(yh2 | (one << 16), one | (nh << 16),
                                        nl, 0u);
  }
}

__global__ __launch_bounds__(TPB, 4) void chamfer_k(
    const float* __restrict__ x, const float* __restrict__ y,
    float* __restrict__ out) {
  __shared__ uint4 ldsFrag[2][32 * 64];   // 2 x 32 KB double buffer
  __shared__ float red[8];

  const unsigned one = 0x3F80u;
  int t = threadIdx.x, lane = t & 63, w = t >> 6;   // 8 waves
  int b = blockIdx.x;                    // 512 blocks
  int dir = b >> 8;                      // 0: rows=x scan y; 1: rows=y scan x
  int bb = b & 255;
  int batch = bb >> 5;
  int rowSeg = bb & 31;                  // 32 segs of 256 rows
  const float* __restrict__ own  = dir ? y : x;
  const float* __restrict__ cand = dir ? x : y;

  // ---- A-frag (one 32-row tile per wave), built in registers ----
  int m = lane & 31;
  int row0 = batch * N_ + rowSeg * 256 + w * 32;
  const float* po = own + 3 * (row0 + m);
  float v0 = po[0], v1 = po[1], v2 = po[2];
  float nv = fmaf(v0, v0, fmaf(v1, v1, v2 * v2));
  float a0 = -2.0f * v0, a1 = -2.0f * v1, a2 = -2.0f * v2;
  unsigned ah0 = b16(a0), ah1 = b16(a1), ah2 = b16(a2);
  unsigned al0 = b16(a0 - bf(ah0)), al1 = b16(a1 - bf(ah1)), al2 = b16(a2 - bf(ah2));
  unsigned nh = b16(nv), nl = b16(nv - bf(nh));
  uint4 h0 = make_uint4(ah0 | (ah1 << 16), ah2 | (ah0 << 16),
                        ah1 | (ah2 << 16), al0 | (al1 << 16));
  uint4 h1 = make_uint4(al2 | (nh << 16), nl | (one << 16), one, 0u);
  uint4 afr;
  afr.x = (lane < 32) ? h0.x : h1.x;
  afr.y = (lane < 32) ? h0.y : h1.y;
  afr.z = (lane < 32) ? h0.z : h1.z;
  afr.w = (lane < 32) ? h0.w : h1.w;
  bf16x8 A = __builtin_bit_cast(bf16x8, afr);

  f32x16 z = {0.f,0.f,0.f,0.f,0.f,0.f,0.f,0.f,0.f,0.f,0.f,0.f,0.f,0.f,0.f,0.f};
  f32x16 rmA, rmB;
#pragma unroll
  for (int r = 0; r < 16; ++r) { rmA[r] = 1e30f; rmB[r] = 1e30f; }

  const float* cbb = cand + batch * N_ * 3;
  build_chunk(cbb, ldsFrag[0], t);
  __syncthreads();

  for (int ch = 0; ch < 8; ++ch) {
    const uint4* cur = ldsFrag[ch & 1];
    if (ch < 7)                          // overlap: build next while computing
      build_chunk(cbb + (ch + 1) * 1024 * 3, ldsFrag[(ch + 1) & 1], t);

#pragma unroll 2
    for (int i = 0; i < 8; ++i) {        // 32 tiles, 4 per iter
      bf16x8 B0 = __builtin_bit_cast(bf16x8, cur[(4 * i + 0) * 64 + lane]);
      bf16x8 B1 = __builtin_bit_cast(bf16x8, cur[(4 * i + 1) * 64 + lane]);
      bf16x8 B2 = __builtin_bit_cast(bf16x8, cur[(4 * i + 2) * 64 + lane]);
      bf16x8 B3 = __builtin_bit_cast(bf16x8, cur[(4 * i + 3) * 64 + lane]);
      f32x16 acc0 = __builtin_amdgcn_mfma_f32_32x32x16_bf16(A, B0, z, 0, 0, 0);
      f32x16 acc1 = __builtin_amdgcn_mfma_f32_32x32x16_bf16(A, B1, z, 0, 0, 0);
      f32x16 acc2 = __builtin_amdgcn_mfma_f32_32x32x16_bf16(A, B2, z, 0, 0, 0);
      f32x16 acc3 = __builtin_amdgcn_mfma_f32_32x32x16_bf16(A, B3, z, 0, 0, 0);
#pragma unroll
      for (int r = 0; r < 16; ++r) {
        rmA[r] = fminf(fminf(rmA[r], acc0[r]), acc1[r]);   // v_min3_f32
        rmB[r] = fminf(fminf(rmB[r], acc2[r]), acc3[r]);   // v_min3_f32
      }
    }
    __syncthreads();                     // next buffer ready / cur free
  }

  // ---- epilogue: fold halves+lanes, sum 32 row-mins, block sum ----
#pragma unroll
  for (int r = 0; r < 16; ++r) rmA[r] = fminf(rmA[r], rmB[r]);
#pragma unroll
  for (int msk = 1; msk <= 16; msk <<= 1) {
#pragma unroll
    for (int r = 0; r < 16; ++r)
      rmA[r] = fminf(rmA[r], __shfl_xor(rmA[r], msk, 64));
  }
  float s = 0.0f;
#pragma unroll
  for (int r = 0; r < 16; ++r) s += rmA[r];
  s += __shfl_xor(s, 32, 64);
  if (lane == 0) red[w] = s;
  __syncthreads();
  if (t == 0) {
    float bs = 0.0f;
#pragma unroll
    for (int c = 0; c < 8; ++c) bs += red[c];
    atomicAdd(out, bs * (1.0f / (float)PTS));
  }
}

extern "C" void kernel_launch(void* const* d_in, const int* in_sizes, int n_in,
                              void* d_out, int out_size, void* d_ws, size_t ws_size,
                              hipStream_t stream) {
  const float* x = (const float*)d_in[0];
  const float* y = (const float*)d_in[1];
  float* out = (float*)d_out;
  hipMemsetAsync(out, 0, sizeof(float), stream);
  chamfer_k<<<512, TPB, 0, stream>>>(x, y, out);
}

// Round 10
// 95.110 us; speedup vs baseline: 5.4098x; 1.0048x over previous
//
#include <hip/hip_runtime.h>

// Chamfer distance, B=8, N=M=8192, D=3, fp32 — MFMA, DS-amortized.
// dist[i][j] = nx_i + ny_j - 2 x_i.y_j; out = mean(min_j) + mean(min_i).
//
// K=16 bf16-split packing (validated R8/R9, absmax ~0):
//   A row = [ah0 ah1 ah2 ah0 ah1 ah2 al0 al1 | al2 nxh nxl 1 1 0 0 0]
//   B col = [yh0 yh1 yh2 yl0 yl1 yl2 yh0 yh1 | yh2 1 1 nyh nyl 0 0 0]
// R10: R9 was DS-pipe-bound (4096 ds_read_b128/CU = 20.5us > min3 6.8us).
//  - A=4 row-tiles per wave: each B-tile LDS read feeds 4 MFMAs -> DS/4.
//  - block = 1024 rows x 4096 cands (half-scan); 128 row-groups x 2 halves
//    = 256 blocks x 512 thr (1/CU, 2 waves/SIMD, launch_bounds(512,2)).
//  - halves merge via per-block row-min slabs in d_ws (plain stores),
//    summed by a tiny final kernel. No atomics on the min path.

#define B_ 8
#define N_ 8192
#define PTS (B_ * N_)        // 65536 per set
#define TPB 512

typedef short bf16x8 __attribute__((ext_vector_type(8)));
typedef float f32x16 __attribute__((ext_vector_type(16)));

__device__ __forceinline__ unsigned b16(float f) {   // fp32 -> bf16 bits (RNE)
  unsigned u = __float_as_uint(f);
  return (u + 0x7FFFu + ((u >> 16) & 1u)) >> 16;
}
__device__ __forceinline__ float bf(unsigned h) { return __uint_as_float(h << 16); }

__device__ __forceinline__ void build_chunk(const float* __restrict__ cb,
                                            uint4* __restrict__ dst, int t) {
  const unsigned one = 0x3F80u;
#pragma unroll
  for (int q = 0; q < 2; ++q) {
    int p = t + q * TPB;                 // contiguous in lane -> no conflicts
    float c0 = cb[3 * p], c1 = cb[3 * p + 1], c2 = cb[3 * p + 2];
    float nc = fmaf(c0, c0, fmaf(c1, c1, c2 * c2));
    unsigned yh0 = b16(c0), yh1 = b16(c1), yh2 = b16(c2);
    unsigned yl0 = b16(c0 - bf(yh0)), yl1 = b16(c1 - bf(yh1)), yl2 = b16(c2 - bf(yh2));
    unsigned nh = b16(nc), nl = b16(nc - bf(nh));
    int tt = p >> 5, mm = p & 31;
    dst[tt * 64 + mm]      = make_uint4(yh0 | (yh1 << 16), yh2 | (yl0 << 16),
                                        yl1 | (yl2 << 16), yh0 | (yh1 << 16));
    dst[tt * 64 + 32 + mm] = make_uint4(yh2 | (one << 16), one | (nh << 16),
                                        nl, 0u);
  }
}

__global__ __launch_bounds__(TPB, 2) void chamfer_main_k(
    const float* __restrict__ x, const float* __restrict__ y,
    float* __restrict__ gpart) {
  __shared__ uint4 ldsFrag[2][32 * 64];   // 2 x 32 KB double buffer

  const unsigned one = 0x3F80u;
  int t = threadIdx.x, lane = t & 63, w = t >> 6;   // 8 waves
  int b = blockIdx.x;                    // 256 blocks
  int g = b >> 1;                        // row-group 0..127 (1024 rows each)
  int hf = b & 1;                        // candidate half (4096 cands)
  int dir = g >> 6;                      // 0: rows=x scan y; 1: rows=y scan x
  int gg = g & 63;
  int batch = gg >> 3;
  int seg = gg & 7;                      // 1024-row segment within batch
  const float* __restrict__ own  = dir ? y : x;
  const float* __restrict__ cand = dir ? x : y;

  // ---- A-frags: 4 row-tiles (128 rows) per wave ----
  int m = lane & 31;
  int rowBase = batch * N_ + seg * 1024 + w * 128;
  bf16x8 A[4];
#pragma unroll
  for (int a = 0; a < 4; ++a) {
    const float* po = own + 3 * (rowBase + a * 32 + m);
    float v0 = po[0], v1 = po[1], v2 = po[2];
    float nv = fmaf(v0, v0, fmaf(v1, v1, v2 * v2));
    float a0 = -2.0f * v0, a1 = -2.0f * v1, a2 = -2.0f * v2;
    unsigned ah0 = b16(a0), ah1 = b16(a1), ah2 = b16(a2);
    unsigned al0 = b16(a0 - bf(ah0)), al1 = b16(a1 - bf(ah1)), al2 = b16(a2 - bf(ah2));
    unsigned nh = b16(nv), nl = b16(nv - bf(nh));
    uint4 h0 = make_uint4(ah0 | (ah1 << 16), ah2 | (ah0 << 16),
                          ah1 | (ah2 << 16), al0 | (al1 << 16));
    uint4 h1 = make_uint4(al2 | (nh << 16), nl | (one << 16), one, 0u);
    uint4 afr;
    afr.x = (lane < 32) ? h0.x : h1.x;
    afr.y = (lane < 32) ? h0.y : h1.y;
    afr.z = (lane < 32) ? h0.z : h1.z;
    afr.w = (lane < 32) ? h0.w : h1.w;
    A[a] = __builtin_bit_cast(bf16x8, afr);
  }

  f32x16 z = {0.f,0.f,0.f,0.f,0.f,0.f,0.f,0.f,0.f,0.f,0.f,0.f,0.f,0.f,0.f,0.f};
  f32x16 rm[4];
#pragma unroll
  for (int a = 0; a < 4; ++a)
#pragma unroll
    for (int r = 0; r < 16; ++r) rm[a][r] = 1e30f;

  const float* cbb = cand + (batch * N_ + hf * 4096) * 3;
  build_chunk(cbb, ldsFrag[0], t);
  __syncthreads();

  for (int ch = 0; ch < 4; ++ch) {       // 4 chunks of 1024 candidates
    const uint4* cur = ldsFrag[ch & 1];
    if (ch < 3)                          // build next while computing
      build_chunk(cbb + (ch + 1) * 1024 * 3, ldsFrag[(ch + 1) & 1], t);

    for (int i = 0; i < 16; ++i) {       // 32 tiles, 2 per iter
      bf16x8 B0 = __builtin_bit_cast(bf16x8, cur[(2 * i) * 64 + lane]);
      bf16x8 B1 = __builtin_bit_cast(bf16x8, cur[(2 * i + 1) * 64 + lane]);
#pragma unroll
      for (int a = 0; a < 4; ++a) {      // per A: 2 MFMA + 16 min3 (32 accs live)
        f32x16 acc0 = __builtin_amdgcn_mfma_f32_32x32x16_bf16(A[a], B0, z, 0, 0, 0);
        f32x16 acc1 = __builtin_amdgcn_mfma_f32_32x32x16_bf16(A[a], B1, z, 0, 0, 0);
#pragma unroll
        for (int r = 0; r < 16; ++r)
          rm[a][r] = fminf(fminf(rm[a][r], acc0[r]), acc1[r]);   // v_min3_f32
      }
    }
    __syncthreads();
  }

  // ---- epilogue: fold 32 cols per half (butterfly), store row-mins ----
#pragma unroll
  for (int a = 0; a < 4; ++a)
#pragma unroll
    for (int msk = 1; msk <= 16; msk <<= 1)
#pragma unroll
      for (int r = 0; r < 16; ++r)
        rm[a][r] = fminf(rm[a][r], __shfl_xor(rm[a][r], msk, 64));

  float* gp = gpart + b * 1024;          // this block's row-min slab
  if ((lane & 31) == 0) {                // lanes 0 and 32 (h = lane>>5)
    int h = lane >> 5;
#pragma unroll
    for (int a = 0; a < 4; ++a)
#pragma unroll
      for (int r = 0; r < 16; ++r)
        gp[w * 128 + a * 32 + (r & 3) + 8 * (r >> 2) + 4 * h] = rm[a][r];
  }
}

// ---- final: min the two candidate-halves, sum everything ----
__global__ __launch_bounds__(256) void chamfer_final_k(
    const float* __restrict__ gpart, float* __restrict__ out) {
  int i = blockIdx.x * 256 + threadIdx.x;   // 32768 threads x 4 rows
  float s = 0.0f;
#pragma unroll
  for (int e = 0; e < 4; ++e) {
    int rowid = 4 * i + e;               // 0 .. 131071
    int g = rowid >> 10, r = rowid & 1023;
    s += fminf(gpart[(2 * g) * 1024 + r], gpart[(2 * g + 1) * 1024 + r]);
  }
  for (int off = 32; off > 0; off >>= 1) s += __shfl_down(s, off, 64);
  __shared__ float red[4];
  int lane = threadIdx.x & 63, wv = threadIdx.x >> 6;
  if (lane == 0) red[wv] = s;
  __syncthreads();
  if (threadIdx.x == 0) {
    float tt = (red[0] + red[1]) + (red[2] + red[3]);
    atomicAdd(out, tt * (1.0f / (float)PTS));
  }
}

extern "C" void kernel_launch(void* const* d_in, const int* in_sizes, int n_in,
                              void* d_out, int out_size, void* d_ws, size_t ws_size,
                              hipStream_t stream) {
  const float* x = (const float*)d_in[0];
  const float* y = (const float*)d_in[1];
  float* out = (float*)d_out;
  float* gpart = (float*)d_ws;           // 256 * 1024 floats = 1 MB

  hipMemsetAsync(out, 0, sizeof(float), stream);
  chamfer_main_k<<<256, TPB, 0, stream>>>(x, y, gpart);
  chamfer_final_k<<<128, 256, 0, stream>>>(gpart, out);
}

// Round 11
// 94.074 us; speedup vs baseline: 5.4694x; 1.0110x over previous
//
#include <hip/hip_runtime.h>

// Chamfer distance, B=8, N=M=8192, D=3, fp32 — MFMA, occupancy+DS balanced.
// dist[i][j] = nx_i + ny_j - 2 x_i.y_j; out = mean(min_j) + mean(min_i).
//
// K=16 bf16-split packing (validated R8-R10, absmax ~0):
//   A row = [ah0 ah1 ah2 ah0 ah1 ah2 al0 al1 | al2 nxh nxl 1 1 0 0 0]
//   B col = [yh0 yh1 yh2 yl0 yl1 yl2 yh0 yh1 | yh2 1 1 nyh nyl 0 0 0]
//
// R11: MFMA-pipe floor is 13.8us/CU (8.07 cyc/CU per 32x32x16, dual-pass).
// R9 had 4 waves/SIMD but DS=20us; R10 had DS=5us but 2 waves/SIMD; both
// stalled ~2-3x over max(pipe). This round: A=2 tiles/wave (DS=10.2us/CU)
// AND 4 waves/SIMD (512 blocks x 512 thr = 2 blocks/CU, launch_bounds(512,4)
// caps VGPR at 128), unroll-2 inner loop for ~8 MFMAs in flight.

#define B_ 8
#define N_ 8192
#define PTS (B_ * N_)        // 65536 per set
#define TPB 512

typedef short bf16x8 __attribute__((ext_vector_type(8)));
typedef float f32x16 __attribute__((ext_vector_type(16)));

__device__ __forceinline__ unsigned b16(float f) {   // fp32 -> bf16 bits (RNE)
  unsigned u = __float_as_uint(f);
  return (u + 0x7FFFu + ((u >> 16) & 1u)) >> 16;
}
__device__ __forceinline__ float bf(unsigned h) { return __uint_as_float(h << 16); }

__device__ __forceinline__ void build_chunk(const float* __restrict__ cb,
                                            uint4* __restrict__ dst, int t) {
  const unsigned one = 0x3F80u;
#pragma unroll
  for (int q = 0; q < 2; ++q) {
    int p = t + q * TPB;                 // contiguous in lane -> no conflicts
    float c0 = cb[3 * p], c1 = cb[3 * p + 1], c2 = cb[3 * p + 2];
    float nc = fmaf(c0, c0, fmaf(c1, c1, c2 * c2));
    unsigned yh0 = b16(c0), yh1 = b16(c1), yh2 = b16(c2);
    unsigned yl0 = b16(c0 - bf(yh0)), yl1 = b16(c1 - bf(yh1)), yl2 = b16(c2 - bf(yh2));
    unsigned nh = b16(nc), nl = b16(nc - bf(nh));
    int tt = p >> 5, mm = p & 31;
    dst[tt * 64 + mm]      = make_uint4(yh0 | (yh1 << 16), yh2 | (yl0 << 16),
                                        yl1 | (yl2 << 16), yh0 | (yh1 << 16));
    dst[tt * 64 + 32 + mm] = make_uint4(yh2 | (one << 16), one | (nh << 16),
                                        nl, 0u);
  }
}

__global__ __launch_bounds__(TPB, 4) void chamfer_main_k(
    const float* __restrict__ x, const float* __restrict__ y,
    float* __restrict__ gpart) {
  __shared__ uint4 ldsFrag[2][32 * 64];   // 2 x 32 KB double buffer

  const unsigned one = 0x3F80u;
  int t = threadIdx.x, lane = t & 63, w = t >> 6;   // 8 waves
  int b = blockIdx.x;                    // 512 blocks
  int g = b >> 1;                        // row-group 0..255 (512 rows each)
  int hf = b & 1;                        // candidate half (4096 cands)
  int dir = g >> 7;                      // 0: rows=x scan y; 1: rows=y scan x
  int gg = g & 127;
  int batch = gg >> 4;
  int seg = gg & 15;                     // 512-row segment within batch
  const float* __restrict__ own  = dir ? y : x;
  const float* __restrict__ cand = dir ? x : y;

  // ---- A-frags: 2 row-tiles (64 rows) per wave ----
  int m = lane & 31;
  int rowBase = batch * N_ + seg * 512 + w * 64;
  bf16x8 A0, A1;
#pragma unroll
  for (int a = 0; a < 2; ++a) {
    const float* po = own + 3 * (rowBase + a * 32 + m);
    float v0 = po[0], v1 = po[1], v2 = po[2];
    float nv = fmaf(v0, v0, fmaf(v1, v1, v2 * v2));
    float a0 = -2.0f * v0, a1 = -2.0f * v1, a2 = -2.0f * v2;
    unsigned ah0 = b16(a0), ah1 = b16(a1), ah2 = b16(a2);
    unsigned al0 = b16(a0 - bf(ah0)), al1 = b16(a1 - bf(ah1)), al2 = b16(a2 - bf(ah2));
    unsigned nh = b16(nv), nl = b16(nv - bf(nh));
    uint4 h0 = make_uint4(ah0 | (ah1 << 16), ah2 | (ah0 << 16),
                          ah1 | (ah2 << 16), al0 | (al1 << 16));
    uint4 h1 = make_uint4(al2 | (nh << 16), nl | (one << 16), one, 0u);
    uint4 afr;
    afr.x = (lane < 32) ? h0.x : h1.x;
    afr.y = (lane < 32) ? h0.y : h1.y;
    afr.z = (lane < 32) ? h0.z : h1.z;
    afr.w = (lane < 32) ? h0.w : h1.w;
    if (a == 0) A0 = __builtin_bit_cast(bf16x8, afr);
    else        A1 = __builtin_bit_cast(bf16x8, afr);
  }

  f32x16 z = {0.f,0.f,0.f,0.f,0.f,0.f,0.f,0.f,0.f,0.f,0.f,0.f,0.f,0.f,0.f,0.f};
  f32x16 rm0, rm1;
#pragma unroll
  for (int r = 0; r < 16; ++r) { rm0[r] = 1e30f; rm1[r] = 1e30f; }

  const float* cbb = cand + (batch * N_ + hf * 4096) * 3;
  build_chunk(cbb, ldsFrag[0], t);
  __syncthreads();

  for (int ch = 0; ch < 4; ++ch) {       // 4 chunks of 1024 candidates
    const uint4* cur = ldsFrag[ch & 1];
    if (ch < 3)                          // build next while computing
      build_chunk(cbb + (ch + 1) * 1024 * 3, ldsFrag[(ch + 1) & 1], t);

#pragma unroll 2
    for (int i = 0; i < 16; ++i) {       // 32 tiles, 2 per iter
      bf16x8 B0 = __builtin_bit_cast(bf16x8, cur[(2 * i) * 64 + lane]);
      bf16x8 B1 = __builtin_bit_cast(bf16x8, cur[(2 * i + 1) * 64 + lane]);
      f32x16 acc0 = __builtin_amdgcn_mfma_f32_32x32x16_bf16(A0, B0, z, 0, 0, 0);
      f32x16 acc1 = __builtin_amdgcn_mfma_f32_32x32x16_bf16(A1, B0, z, 0, 0, 0);
      f32x16 acc2 = __builtin_amdgcn_mfma_f32_32x32x16_bf16(A0, B1, z, 0, 0, 0);
      f32x16 acc3 = __builtin_amdgcn_mfma_f32_32x32x16_bf16(A1, B1, z, 0, 0, 0);
#pragma unroll
      for (int r = 0; r < 16; ++r) {
        rm0[r] = fminf(fminf(rm0[r], acc0[r]), acc2[r]);   // v_min3_f32
        rm1[r] = fminf(fminf(rm1[r], acc1[r]), acc3[r]);   // v_min3_f32
      }
    }
    __syncthreads();
  }

  // ---- epilogue: fold 32 cols per half (butterfly), store row-mins ----
#pragma unroll
  for (int msk = 1; msk <= 16; msk <<= 1)
#pragma unroll
    for (int r = 0; r < 16; ++r) {
      rm0[r] = fminf(rm0[r], __shfl_xor(rm0[r], msk, 64));
      rm1[r] = fminf(rm1[r], __shfl_xor(rm1[r], msk, 64));
    }

  float* gp = gpart + b * 512;           // this block's row-min slab
  if ((lane & 31) == 0) {                // lanes 0 and 32 (h = lane>>5)
    int h = lane >> 5;
#pragma unroll
    for (int r = 0; r < 16; ++r) {
      int rr = (r & 3) + 8 * (r >> 2) + 4 * h;
      gp[w * 64 + rr] = rm0[r];
      gp[w * 64 + 32 + rr] = rm1[r];
    }
  }
}

// ---- final: min the two candidate-halves, sum everything ----
__global__ __launch_bounds__(256) void chamfer_final_k(
    const float* __restrict__ gpart, float* __restrict__ out) {
  int i = blockIdx.x * 256 + threadIdx.x;   // 32768 threads x 4 rows
  float s = 0.0f;
#pragma unroll
  for (int e = 0; e < 4; ++e) {
    int rowid = 4 * i + e;               // 0 .. 131071
    int g = rowid >> 9, r = rowid & 511;
    s += fminf(gpart[(2 * g) * 512 + r], gpart[(2 * g + 1) * 512 + r]);
  }
  for (int off = 32; off > 0; off >>= 1) s += __shfl_down(s, off, 64);
  __shared__ float red[4];
  int lane = threadIdx.x & 63, wv = threadIdx.x >> 6;
  if (lane == 0) red[wv] = s;
  __syncthreads();
  if (threadIdx.x == 0) {
    float tt = (red[0] + red[1]) + (red[2] + red[3]);
    atomicAdd(out, tt * (1.0f / (float)PTS));
  }
}

extern "C" void kernel_launch(void* const* d_in, const int* in_sizes, int n_in,
                              void* d_out, int out_size, void* d_ws, size_t ws_size,
                              hipStream_t stream) {
  const float* x = (const float*)d_in[0];
  const float* y = (const float*)d_in[1];
  float* out = (float*)d_out;
  float* gpart = (float*)d_ws;           // 512 * 512 floats = 1 MB

  hipMemsetAsync(out, 0, sizeof(float), stream);
  chamfer_main_k<<<512, TPB, 0, stream>>>(x, y, gpart);
  chamfer_final_k<<<128, 256, 0, stream>>>(gpart, out);
}